// Round 1
// baseline (74.022 us; speedup 1.0000x reference)
//
#include <hip/hip_runtime.h>
#include <stdint.h>

#define VOCAB     128000
#define NB4       (VOCAB / 4)
#define BINS      4096
#define CAND_CAP  2048
#define KEEP_CAP  128

// Gumbel random-bits scheme:
//   2 = JAX partitionable threefry (default since jax 0.4.36): bits = o0 ^ o1 of threefry(key,(0,idx))
//   1 = legacy split-iota: halves scheme
#define BITS_SCHEME 2

__device__ __forceinline__ uint32_t rotl32(uint32_t x, uint32_t r) {
    return (x << r) | (x >> (32u - r));
}

// monotone float -> uint transform (total order)
__device__ __forceinline__ uint32_t f2ord(float f) {
    uint32_t u = __float_as_uint(f);
    return (u & 0x80000000u) ? ~u : (u | 0x80000000u);
}

// Threefry-2x32, 20 rounds, key = (0, 42)  [jax.random.key(42)]
__device__ __forceinline__ void threefry_0_42(uint32_t x0, uint32_t x1,
                                              uint32_t& o0, uint32_t& o1) {
    const uint32_t k0 = 0u, k1 = 42u;
    const uint32_t k2 = 0x1BD11BDAu ^ k0 ^ k1;
#define TF_RND(R) { x0 += x1; x1 = rotl32(x1, (R)); x1 ^= x0; }
    x0 += k0; x1 += k1;
    TF_RND(13) TF_RND(15) TF_RND(26) TF_RND(6)
    x0 += k1; x1 += k2 + 1u;
    TF_RND(17) TF_RND(29) TF_RND(16) TF_RND(24)
    x0 += k2; x1 += k0 + 2u;
    TF_RND(13) TF_RND(15) TF_RND(26) TF_RND(6)
    x0 += k0; x1 += k1 + 3u;
    TF_RND(17) TF_RND(29) TF_RND(16) TF_RND(24)
    x0 += k1; x1 += k2 + 4u;
    TF_RND(13) TF_RND(15) TF_RND(26) TF_RND(6)
    x0 += k2; x1 += k0 + 5u;
#undef TF_RND
    o0 = x0; o1 = x1;
}

__device__ __forceinline__ float gumbel_at(uint64_t flat, uint64_t total) {
    uint32_t bits, o0, o1;
#if BITS_SCHEME == 2
    // partitionable: counts are 64-bit flat indices; here hi32 == 0
    threefry_0_42(0u, (uint32_t)flat, o0, o1);
    bits = o0 ^ o1;
#else
    // legacy: iota split in halves; (i, i+h) -> o0 for i<h, (i-h, i) -> o1 otherwise
    uint64_t h = total >> 1;
    if (flat < h) { threefry_0_42((uint32_t)flat, (uint32_t)(flat + h), o0, o1); bits = o0; }
    else          { threefry_0_42((uint32_t)(flat - h), (uint32_t)flat, o0, o1); bits = o1; }
#endif
    // uniform in [tiny, 1): bitcast trick, exactly as jax._src.random._uniform
    float f = __uint_as_float((bits >> 9) | 0x3F800000u) - 1.0f;
    float u = (f == 0.0f) ? 1.17549435e-38f : f;
    return -logf(-logf(u));
}

extern "C" __global__ __launch_bounds__(1024)
void sample_topk_topp_kernel(const float* __restrict__ logits,
                             const float* __restrict__ temp_p,
                             const float* __restrict__ topp_p,
                             const int*   __restrict__ topk_p,
                             float* __restrict__ out,
                             int batch) {
    const int row  = blockIdx.x;
    const int tid  = threadIdx.x;
    const int nthr = blockDim.x;

    const float T      = temp_p[0];
    const float thresh = 1.0f - topp_p[0];   // same float op as reference
    const int   K      = topk_p[0];

    __shared__ int   hist[BINS];
    __shared__ float candV[CAND_CAP];
    __shared__ int   candI[CAND_CAP];
    __shared__ int   s_grp[256];
    __shared__ int   s_cnt;
    __shared__ int   s_tbin;
    __shared__ float keptP[KEEP_CAP];
    __shared__ int   keptI[KEEP_CAP];
    __shared__ float s_gs[KEEP_CAP];
    __shared__ int   s_M;
    __shared__ int   s_token;

    for (int i = tid; i < BINS; i += nthr) hist[i] = 0;
    if (tid == 0) s_cnt = 0;
    __syncthreads();

    const float4* rowp = (const float4*)(logits + (size_t)row * VOCAB);

    // ---- pass 1: 12-bit radix histogram of scores = logits / T ----
    for (int i = tid; i < NB4; i += nthr) {
        float4 v = rowp[i];
        atomicAdd(&hist[f2ord(v.x / T) >> 20], 1);
        atomicAdd(&hist[f2ord(v.y / T) >> 20], 1);
        atomicAdd(&hist[f2ord(v.z / T) >> 20], 1);
        atomicAdd(&hist[f2ord(v.w / T) >> 20], 1);
    }
    __syncthreads();

    // group sums (256 groups of 16 bins) then serial top-down scan by thread 0
    if (tid < 256) {
        int s = 0;
        #pragma unroll
        for (int b = 0; b < 16; ++b) s += hist[tid * 16 + b];
        s_grp[tid] = s;
    }
    __syncthreads();
    if (tid == 0) {
        int cum = 0, tb = 0;
        int g = 255;
        for (; g > 0; --g) {
            if (cum + s_grp[g] >= K) break;
            cum += s_grp[g];
        }
        for (int b = g * 16 + 15; ; --b) {
            cum += hist[b];
            if (cum >= K || b == g * 16) { tb = b; break; }
        }
        s_tbin = tb;
    }
    __syncthreads();
    const uint32_t tbin = (uint32_t)s_tbin;

    // ---- pass 2: collect all candidates with bin >= tbin ----
    for (int i = tid; i < NB4; i += nthr) {
        float4 v = rowp[i];
        float s[4] = { v.x / T, v.y / T, v.z / T, v.w / T };
        #pragma unroll
        for (int c = 0; c < 4; ++c) {
            if ((f2ord(s[c]) >> 20) >= tbin) {
                int p = atomicAdd(&s_cnt, 1);
                if (p < CAND_CAP) { candV[p] = s[c]; candI[p] = 4 * i + c; }
            }
        }
    }
    __syncthreads();
    const int n = min(s_cnt, CAND_CAP);

    // ---- rank sort descending (unique total order via index tiebreak) ----
    float* sortedV = (float*)hist;          // reuse hist LDS
    int*   sortedI = hist + CAND_CAP;
    for (int j = tid; j < n; j += nthr) {
        float vj = candV[j]; int ij = candI[j];
        int r = 0;
        for (int l = 0; l < n; ++l) {
            float vl = candV[l];
            r += (vl > vj) || (vl == vj && candI[l] < ij);
        }
        sortedV[r] = vj; sortedI[r] = ij;
    }
    __syncthreads();

    // ---- serial small math: top-k kth, top-p cut, final softmax ----
    if (tid == 0) {
        int Keff = min(K, n);
        float kth = sortedV[Keff - 1];
        int Kp = Keff;
        while (Kp < n && sortedV[Kp] == kth) ++Kp;   // scores >= kth all survive

        float m = sortedV[0];
        float Z = 0.0f;
        for (int j = Kp - 1; j >= 0; --j) Z += expf(sortedV[j] - m);  // ascending sum, like cumsum path
        // ascending cumulative prob; remove while cum <= 1 - top_p
        float cum = 0.0f; int jcut = 0;
        for (int j = Kp - 1; j >= 0; --j) {
            cum += expf(sortedV[j] - m) / Z;
            if (cum > thresh) { jcut = j; break; }
        }
        int M = jcut + 1;
        if (M > KEEP_CAP) M = KEEP_CAP;
        float Z2 = 0.0f;
        for (int j = 0; j < M; ++j) Z2 += expf(sortedV[j] - m);
        for (int j = 0; j < M; ++j) {
            keptP[j] = expf(sortedV[j] - m) / Z2;
            keptI[j] = sortedI[j];
        }
        s_M = M;
    }
    __syncthreads();
    const int M = s_M;

    // ---- gumbel at surviving indices, argmax (first-index tiebreak) ----
    if (tid < M) {
        uint64_t flat = (uint64_t)row * VOCAB + (uint32_t)keptI[tid];
        float g = gumbel_at(flat, (uint64_t)batch * VOCAB);
        s_gs[tid] = sortedV[tid] + g;
    }
    __syncthreads();
    if (tid == 0) {
        float bs = -__builtin_inff(); int bi = 0x7fffffff;
        for (int j = 0; j < M; ++j) {
            float s = s_gs[j]; int c = keptI[j];
            if (s > bs || (s == bs && c < bi)) { bs = s; bi = c; }
        }
        s_token = bi;
    }

    // ---- write output: zero the probs row, scatter kept probs, token ----
    __syncthreads();
    float4* orow = (float4*)(out + batch + (size_t)row * VOCAB);
    const float4 z4 = make_float4(0.0f, 0.0f, 0.0f, 0.0f);
    for (int i = tid; i < NB4; i += nthr) orow[i] = z4;
    __syncthreads();
    for (int j = tid; j < M; j += nthr) {
        out[batch + (size_t)row * VOCAB + keptI[j]] = keptP[j];
    }
    if (tid == 0) out[row] = (float)s_token;
}

extern "C" void kernel_launch(void* const* d_in, const int* in_sizes, int n_in,
                              void* d_out, int out_size, void* d_ws, size_t ws_size,
                              hipStream_t stream) {
    (void)n_in; (void)out_size; (void)d_ws; (void)ws_size;
    const float* logits = (const float*)d_in[0];
    const float* temp   = (const float*)d_in[1];
    const float* topp   = (const float*)d_in[2];
    const int*   topk   = (const int*)d_in[3];
    int batch = in_sizes[0] / VOCAB;
    sample_topk_topp_kernel<<<batch, 1024, 0, stream>>>(
        logits, temp, topp, topk, (float*)d_out, batch);
}